// Round 1
// 299.350 us; speedup vs baseline: 1.1603x; 1.1603x over previous
//
#include <hip/hip_runtime.h>
#include <hip/hip_bf16.h>

#define D 1024
#define H 16
#define DH 64
#define KN 32768
#define EPS 1e-5f

__device__ __forceinline__ float wave_sum(float v){
  #pragma unroll
  for (int off = 32; off; off >>= 1) v += __shfl_xor(v, off, 64);
  return v;
}

#define GLL(gp, lp) __builtin_amdgcn_global_load_lds((const __attribute__((address_space(1))) void*)(gp), (__attribute__((address_space(3))) void*)(lp), 16, 0, 0)

// K1: q[j] = query . wq_row(j) + bq[j]   (one wave per output)
__global__ void g_qproj(const float* __restrict__ query, const float* __restrict__ ipw,
                        const float* __restrict__ ipb, float* __restrict__ q){
  int j = blockIdx.x, l = threadIdx.x;
  const float4* qv = (const float4*)(query + l*16);
  const float4* wv = (const float4*)(ipw + (size_t)j*D + l*16);
  float acc = 0.f;
  #pragma unroll
  for (int t = 0; t < 4; t++){
    float4 a = qv[t], b = wv[t];
    acc += a.x*b.x + a.y*b.y + a.z*b.z + a.w*b.w;
  }
  acc = wave_sum(acc);
  if (l == 0) q[j] = acc + ipb[j];
}

// K2: qk[h][col] = sum_j q_h[j]*wk[h*64+j][col]  (coalesced row-wise reads)
__global__ __launch_bounds__(256) void g_qk(const float* __restrict__ ipw, const float* __restrict__ ipb,
                                            const float* __restrict__ q, float* __restrict__ qk,
                                            float* __restrict__ sb){
  int b = blockIdx.x, t = threadIdx.x;
  int h = b >> 2, sl = b & 3;
  int jg = t >> 6, c = t & 63;
  __shared__ float qh[DH];
  __shared__ float4 red[256];
  if (t < DH) qh[t] = q[h*DH + t];
  __syncthreads();
  if (t < DH){
    float p = qh[t] * ipb[D + h*DH + t];
    p = wave_sum(p);
    if (t == 0 && sl == 0) sb[h] = p;
  }
  float4 acc = make_float4(0.f,0.f,0.f,0.f);
  for (int jj = 0; jj < 16; jj++){
    int j = jg*16 + jj;
    float4 w = *((const float4*)(ipw + (size_t)(D + h*DH + j)*D) + sl*64 + c);
    float qj = qh[j];
    acc.x += qj*w.x; acc.y += qj*w.y; acc.z += qj*w.z; acc.w += qj*w.w;
  }
  red[t] = acc;
  __syncthreads();
  if (jg == 0){
    float4 a = red[c], b1 = red[64+c], c1 = red[128+c], d1 = red[192+c];
    float4 r = make_float4(a.x+b1.x+c1.x+d1.x, a.y+b1.y+c1.y+d1.y,
                           a.z+b1.z+c1.z+d1.z, a.w+b1.w+c1.w+d1.w);
    ((float4*)(qk + h*D))[sl*64 + c] = r;
  }
}

// K3: fused scoreless attention, v2.
// 256 threads = 4 waves; wave w owns heads {4w..4w+3} (qk frags in 64 VGPRs).
// Per row: 4 per-head dot partials -> reduce-scatter butterfly (8 cross-lane ops),
// head g total lands in lane group g=(ci>>4); one exp per lane; 4 readlane
// broadcasts feed the 64-FMA accumulate. LDS read amplification 4x (was 16x).
// 8-row tiles, 32 KiB each, double-buffered (64 KiB LDS) -> 2 independent blocks/CU.
__global__ __launch_bounds__(256, 2) void g_attn(const float* __restrict__ nbr, const float* __restrict__ qk,
                       const float* __restrict__ sb, float* __restrict__ lpart,
                       float* __restrict__ part, int rows_per_blk){
  __shared__ __align__(16) float tile[2][8*D];   // 64 KiB
  const int t = threadIdx.x;
  const int w = t >> 6, ci = t & 63;
  const int wb = t & ~63;                 // wave-uniform lane base
  const int g = (ci >> 4) & 3;            // scatter group -> head w*4+g
  const float sbl = sb[w*4 + g];

  float qk0[16], qk1[16], qk2[16], qk3[16];
  {
    const float4* p0 = (const float4*)(qk + (w*4+0)*D);
    const float4* p1 = (const float4*)(qk + (w*4+1)*D);
    const float4* p2 = (const float4*)(qk + (w*4+2)*D);
    const float4* p3 = (const float4*)(qk + (w*4+3)*D);
    #pragma unroll
    for (int c = 0; c < 4; c++){
      float4 f;
      f = p0[c*64 + ci]; qk0[4*c]=f.x; qk0[4*c+1]=f.y; qk0[4*c+2]=f.z; qk0[4*c+3]=f.w;
      f = p1[c*64 + ci]; qk1[4*c]=f.x; qk1[4*c+1]=f.y; qk1[4*c+2]=f.z; qk1[4*c+3]=f.w;
      f = p2[c*64 + ci]; qk2[4*c]=f.x; qk2[4*c+1]=f.y; qk2[4*c+2]=f.z; qk2[4*c+3]=f.w;
      f = p3[c*64 + ci]; qk3[4*c]=f.x; qk3[4*c+1]=f.y; qk3[4*c+2]=f.z; qk3[4*c+3]=f.w;
    }
  }
  float acc0[16], acc1[16], acc2[16], acc3[16];
  #pragma unroll
  for (int i = 0; i < 16; i++){ acc0[i]=0.f; acc1[i]=0.f; acc2[i]=0.f; acc3[i]=0.f; }
  float lsum = 0.f;

  const int k0 = blockIdx.x * rows_per_blk;
  const int ntiles = rows_per_blk >> 3;
  const uint4* gb = (const uint4*)nbr;

  // prefetch tile 0: 8 rows = 2048 float4s, 8 per thread
  {
    const uint4* gsrc = gb + (size_t)k0*256;
    #pragma unroll
    for (int i = 0; i < 8; i++) GLL(gsrc + i*256 + t, &tile[0][(i*256 + wb)*4]);
  }
  __syncthreads();

  #pragma unroll 1
  for (int tl = 0; tl < ntiles; tl++){
    int cur = tl & 1;
    if (tl + 1 < ntiles){
      const uint4* gsrc = gb + (size_t)(k0 + (tl+1)*8)*256;
      #pragma unroll
      for (int i = 0; i < 8; i++) GLL(gsrc + i*256 + t, &tile[cur^1][(i*256 + wb)*4]);
    }
    #pragma unroll 1
    for (int r = 0; r < 8; r++){
      const float4* row4 = (const float4*)(tile[cur]) + r*256;
      float xf[16];
      float s0=0.f, s1=0.f, s2=0.f, s3=0.f;
      #pragma unroll
      for (int c = 0; c < 4; c++){
        float4 a = row4[c*64 + ci];          // stride-1 across lanes: conflict-free
        xf[4*c]=a.x; xf[4*c+1]=a.y; xf[4*c+2]=a.z; xf[4*c+3]=a.w;
        s0 += a.x*qk0[4*c] + a.y*qk0[4*c+1] + a.z*qk0[4*c+2] + a.w*qk0[4*c+3];
        s1 += a.x*qk1[4*c] + a.y*qk1[4*c+1] + a.z*qk1[4*c+2] + a.w*qk1[4*c+3];
        s2 += a.x*qk2[4*c] + a.y*qk2[4*c+1] + a.z*qk2[4*c+2] + a.w*qk2[4*c+3];
        s3 += a.x*qk3[4*c] + a.y*qk3[4*c+1] + a.z*qk3[4*c+2] + a.w*qk3[4*c+3];
      }
      // reduce-scatter butterfly: head g total ends in all lanes of group g
      const bool lo32 = (ci & 32) == 0;
      float za = lo32 ? s2 : s0;
      float ka = lo32 ? s0 : s2;
      float u02 = ka + __shfl_xor(za, 32, 64);   // heads 0/2 pair-sums
      float zb = lo32 ? s3 : s1;
      float kb = lo32 ? s1 : s3;
      float u13 = kb + __shfl_xor(zb, 32, 64);   // heads 1/3 pair-sums
      const bool lo16 = (ci & 16) == 0;
      float zc = lo16 ? u13 : u02;
      float kc = lo16 ? u02 : u13;
      float v = kc + __shfl_xor(zc, 16, 64);
      v += __shfl_xor(v, 8, 64);
      v += __shfl_xor(v, 4, 64);
      v += __shfl_xor(v, 2, 64);
      v += __shfl_xor(v, 1, 64);
      float pv = __expf((v + sbl)*0.125f);
      lsum += pv;                                 // all lanes of group g identical
      float p0 = __shfl(pv, 0, 64);
      float p1 = __shfl(pv, 16, 64);
      float p2 = __shfl(pv, 32, 64);
      float p3 = __shfl(pv, 48, 64);
      #pragma unroll
      for (int j = 0; j < 16; j++){
        acc0[j] += p0*xf[j];
        acc1[j] += p1*xf[j];
        acc2[j] += p2*xf[j];
        acc3[j] += p3*xf[j];
      }
    }
    __syncthreads();
  }

  if ((ci & 15) == 0) lpart[blockIdx.x*H + w*4 + g] = lsum;
  float4* o = (float4*)(part + (size_t)blockIdx.x*(H*D) + (size_t)(w*4)*D);
  #pragma unroll
  for (int c = 0; c < 4; c++){
    o[0*256 + c*64 + ci] = make_float4(acc0[4*c], acc0[4*c+1], acc0[4*c+2], acc0[4*c+3]);
    o[1*256 + c*64 + ci] = make_float4(acc1[4*c], acc1[4*c+1], acc1[4*c+2], acc1[4*c+3]);
    o[2*256 + c*64 + ci] = make_float4(acc2[4*c], acc2[4*c+1], acc2[4*c+2], acc2[4*c+3]);
    o[3*256 + c*64 + ci] = make_float4(acc3[4*c], acc3[4*c+1], acc3[4*c+2], acc3[4*c+3]);
  }
}

// K4: nb[o] = sum_b part[b][o] with 4-way K-split per block (256 working blocks);
// block 256 reduces lpart -> lh.
__global__ __launch_bounds__(256) void g_red(const float* __restrict__ part, const float* __restrict__ lpart,
                                             float* __restrict__ nb, float* __restrict__ lh, int nblk){
  int b = blockIdx.x, t = threadIdx.x;
  __shared__ float red[256];
  if (b == 256){
    int h = t & 15, cs = t >> 4;          // 16 slices over nblk
    int per = nblk >> 4;
    float s = 0.f;
    for (int k = 0; k < per; k++) s += lpart[(cs*per + k)*H + h];
    red[t] = s;
    __syncthreads();
    if (t < 16){
      float a = 0.f;
      #pragma unroll
      for (int i = 0; i < 16; i++) a += red[i*16 + t];
      lh[t] = a;
    }
    return;
  }
  int o0 = b * 64;
  int oo = t & 63, cs = t >> 6;           // 4 slices over nblk
  int per = nblk >> 2;
  float s = 0.f;
  #pragma unroll 8
  for (int k = 0; k < per; k++) s += part[(size_t)(cs*per + k)*(H*D) + o0 + oo];
  red[t] = s;
  __syncthreads();
  if (t < 64) nb[o0 + t] = red[t] + red[64+t] + red[128+t] + red[192+t];
}

// K5: ctx[j] = wv_row(j) . (nb[h]/lh[h]) + bv[j]
__global__ void g_ctx(const float* __restrict__ ipw, const float* __restrict__ ipb,
                      const float* __restrict__ nb, const float* __restrict__ lh,
                      float* __restrict__ ctx){
  int j = blockIdx.x, l = threadIdx.x, h = j >> 6;
  const float4* wv = (const float4*)(ipw + (size_t)(2*D + j)*D + l*16);
  const float4* nv = (const float4*)(nb + h*D + l*16);
  float acc = 0.f;
  #pragma unroll
  for (int t = 0; t < 4; t++){
    float4 b = wv[t], n = nv[t];
    acc += b.x*n.x + b.y*n.y + b.z*n.z + b.w*n.w;
  }
  acc = wave_sum(acc);
  if (l == 0) ctx[j] = acc/lh[h] + ipb[2*D + j];
}

// K6: xb[j] = query[j] + out_proj_w_row(j) . ctx + out_proj_b[j]
__global__ void g_attnout(const float* __restrict__ opw, const float* __restrict__ opb,
                          const float* __restrict__ query, const float* __restrict__ ctx,
                          float* __restrict__ xb){
  int j = blockIdx.x, l = threadIdx.x;
  const float4* wv = (const float4*)(opw + (size_t)j*D + l*16);
  const float4* cv = (const float4*)(ctx + l*16);
  float acc = 0.f;
  #pragma unroll
  for (int t = 0; t < 4; t++){
    float4 b = wv[t], c = cv[t];
    acc += b.x*c.x + b.y*c.y + b.z*c.z + b.w*c.w;
  }
  acc = wave_sum(acc);
  if (l == 0) xb[j] = query[j] + acc + opb[j];
}

// K7: fused LN1 + FFN1. 256 blocks x 256 thr; block computes LN(xb) locally into LDS,
// block 0 also persists it to xln (needed for final residual); then 16 gelu-matvec rows.
__global__ __launch_bounds__(256) void g_ffn1(const float* __restrict__ w1, const float* __restrict__ b1,
                                              const float* __restrict__ xb,
                                              const float* __restrict__ g1, const float* __restrict__ be1,
                                              float* __restrict__ xln, float* __restrict__ h1){
  int t = threadIdx.x, b = blockIdx.x;
  __shared__ float xs[D];
  __shared__ float red[8];
  float4 v = ((const float4*)xb)[t];
  float s = wave_sum(v.x + v.y + v.z + v.w);
  if ((t & 63) == 0) red[t >> 6] = s;
  __syncthreads();
  float m = (red[0]+red[1]+red[2]+red[3]) * (1.0f/D);
  float4 d = make_float4(v.x-m, v.y-m, v.z-m, v.w-m);
  float s2 = wave_sum(d.x*d.x + d.y*d.y + d.z*d.z + d.w*d.w);
  if ((t & 63) == 0) red[4 + (t >> 6)] = s2;
  __syncthreads();
  float var = (red[4]+red[5]+red[6]+red[7]) * (1.0f/D);
  float rs = rsqrtf(var + EPS);
  float4 gg = ((const float4*)g1)[t], bb = ((const float4*)be1)[t];
  float4 r = make_float4(d.x*rs*gg.x + bb.x, d.y*rs*gg.y + bb.y,
                         d.z*rs*gg.z + bb.z, d.w*rs*gg.w + bb.w);
  ((float4*)xs)[t] = r;
  if (b == 0) ((float4*)xln)[t] = r;
  __syncthreads();

  int w = t >> 6, l = t & 63;
  const float4* xs4 = (const float4*)xs;
  #pragma unroll 1
  for (int rr = 0; rr < 4; rr++){
    int j = b*16 + w*4 + rr;
    const float4* wr = (const float4*)(w1 + (size_t)j*D);
    float a = 0.f;
    #pragma unroll
    for (int c = 0; c < 4; c++){
      float4 ww = wr[c*64 + l], xx = xs4[c*64 + l];
      a += ww.x*xx.x + ww.y*xx.y + ww.z*xx.z + ww.w*xx.w;
    }
    a = wave_sum(a);
    if (l == 0){
      float z = a + b1[j];
      h1[j] = 0.5f*z*(1.0f + erff(z*0.70710678118654752f));
    }
  }
}

// K8: y[j] = w2_row(j) . h1 + b2[j]   (row length 4096)
__global__ void g_ffn2(const float* __restrict__ w2, const float* __restrict__ b2v,
                       const float* __restrict__ h1, float* __restrict__ y){
  int j = blockIdx.x, l = threadIdx.x;
  const float4* wv = (const float4*)(w2 + (size_t)j*4096 + l*64);
  const float4* hv = (const float4*)(h1 + l*64);
  float acc = 0.f;
  #pragma unroll
  for (int t = 0; t < 16; t++){
    float4 b = wv[t], hh = hv[t];
    acc += b.x*hh.x + b.y*hh.y + b.z*hh.z + b.w*hh.w;
  }
  acc = wave_sum(acc);
  if (l == 0) y[j] = acc + b2v[j];
}

// K9: out = LN(xln + y)*g2 + be2
__global__ __launch_bounds__(1024) void g_ln2(const float* __restrict__ xln, const float* __restrict__ y,
                                              const float* __restrict__ g, const float* __restrict__ be,
                                              float* __restrict__ out){
  int t = threadIdx.x;
  __shared__ float red[16];
  __shared__ float bc;
  float v = xln[t] + y[t];
  float s = wave_sum(v);
  if ((t & 63) == 0) red[t >> 6] = s;
  __syncthreads();
  if (t == 0){ float a = 0.f; for (int i = 0; i < 16; i++) a += red[i]; bc = a*(1.0f/D); }
  __syncthreads();
  float m = bc;
  float d = v - m;
  float s2 = wave_sum(d*d);
  if ((t & 63) == 0) red[t >> 6] = s2;
  __syncthreads();
  if (t == 0){ float a = 0.f; for (int i = 0; i < 16; i++) a += red[i]; bc = a*(1.0f/D); }
  __syncthreads();
  float rs = rsqrtf(bc + EPS);
  out[t] = d*rs*g[t] + be[t];
}

extern "C" void kernel_launch(void* const* d_in, const int* in_sizes, int n_in,
                              void* d_out, int out_size, void* d_ws, size_t ws_size,
                              hipStream_t stream) {
  const float* query = (const float*)d_in[0];
  const float* nbr   = (const float*)d_in[1];
  const float* ipw   = (const float*)d_in[2];
  const float* ipb   = (const float*)d_in[3];
  const float* opw   = (const float*)d_in[4];
  const float* opb   = (const float*)d_in[5];
  const float* w1    = (const float*)d_in[6];
  const float* b1    = (const float*)d_in[7];
  const float* w2    = (const float*)d_in[8];
  const float* b2v   = (const float*)d_in[9];
  const float* g1    = (const float*)d_in[10];
  const float* be1   = (const float*)d_in[11];
  const float* g2    = (const float*)d_in[12];
  const float* be2   = (const float*)d_in[13];

  float* ws    = (float*)d_ws;
  float* q     = ws;               // 1024
  float* qk    = q + D;            // 16384
  float* sb    = qk + H*D;         // 16
  float* lh    = sb + 16;          // 16
  float* ctx   = lh + 16;          // 1024
  float* xb    = ctx + D;          // 1024
  float* xln   = xb + D;           // 1024
  float* h1    = xln + D;          // 4096
  float* y     = h1 + 4*D;         // 1024
  float* nb    = y + D;            // 16384
  float* lpart = nb + H*D;         // 512*16 = 8192 (max)
  float* part  = lpart + 8192;     // nblk*16384

  size_t fixed_bytes = (size_t)(part - ws) * 4;
  int nblk = 512;
  while (nblk > 64 && fixed_bytes + (size_t)nblk*H*D*4 > ws_size) nblk >>= 1;
  int rows_per_blk = KN / nblk;

  g_qproj  <<<1024, 64, 0, stream>>>(query, ipw, ipb, q);
  g_qk     <<<64, 256, 0, stream>>>(ipw, ipb, q, qk, sb);
  g_attn   <<<nblk, 256, 0, stream>>>(nbr, qk, sb, lpart, part, rows_per_blk);
  g_red    <<<257, 256, 0, stream>>>(part, lpart, nb, lh, nblk);
  g_ctx    <<<1024, 64, 0, stream>>>(ipw, ipb, nb, lh, ctx);
  g_attnout<<<1024, 64, 0, stream>>>(opw, opb, query, ctx, xb);
  g_ffn1   <<<256, 256, 0, stream>>>(w1, b1, xb, g1, be1, xln, h1);
  g_ffn2   <<<1024, 64, 0, stream>>>(w2, b2v, h1, y);
  g_ln2    <<<1, 1024, 0, stream>>>(xln, y, g2, be2, (float*)d_out);
}